// Round 1
// baseline (389.517 us; speedup 1.0000x reference)
//
#include <hip/hip_runtime.h>
#include <cstdint>

#define CD 64
#define HWD 589824
#define NTILE 32
#define TILES (HWD / NTILE)        // 18432
#define K1_BLOCKS 512
#define K1_WAVES (K1_BLOCKS * 4)   // 2048
#define TPW (TILES / K1_WAVES)     // 9
#define FMAXV 3.402823466e+38f

typedef float f32x16 __attribute__((ext_vector_type(16)));
typedef short bf16x8 __attribute__((ext_vector_type(8)));

__device__ __forceinline__ short f2bf(float f) {
    unsigned u = __float_as_uint(f);
    u = u + 0x7FFFu + ((u >> 16) & 1u);   // round-to-nearest-even
    return (short)(u >> 16);
}

// Insert d into 16-elem smallest-list (lst, current max cm). Static indexing only.
#define SCREEN(d, lst, cm)                                                  \
    if ((d) < (cm)) {                                                       \
        bool rep = false;                                                   \
        _Pragma("unroll")                                                   \
        for (int j = 0; j < 16; ++j)                                        \
            if (!rep && lst[j] == (cm)) { lst[j] = (d); rep = true; }       \
        cm = lst[0];                                                        \
        _Pragma("unroll")                                                   \
        for (int j = 1; j < 16; ++j) cm = fmaxf(cm, lst[j]);                \
    }

// K1: stream f2, compute d^T tiles (rows=n, cols=p) via MFMA, keep per-lane top-16.
__global__ __launch_bounds__(256) void k1_disttop(
    const float* __restrict__ f1, const float* __restrict__ f2,
    const int* __restrict__ nidx, float* __restrict__ cand)
{
    const int lane = threadIdx.x & 63;
    const int wid  = threadIdx.x >> 6;
    const int gw   = blockIdx.x * 4 + wid;     // 0..2047
    const int l31  = lane & 31;
    const int lh   = lane >> 5;                // k-half

    // sel B-fragments: col p = l31 + 32*b, k = 16*ks + 8*lh + j
    bf16x8 selfrag[2][4];
    float sel20, sel21;
#pragma unroll
    for (int b = 0; b < 2; ++b) {
        int p = l31 + 32 * b;
        long col = (long)nidx[p];
        float s2 = 0.f;
#pragma unroll
        for (int ks = 0; ks < 4; ++ks) {
            bf16x8 fr;
#pragma unroll
            for (int j = 0; j < 8; ++j) {
                int k = 16 * ks + 8 * lh + j;
                float v = f1[(long)k * HWD + col];
                s2 += v * v;
                fr[j] = f2bf(v);
            }
            selfrag[b][ks] = fr;
        }
        s2 += __shfl_xor(s2, 32);  // combine k-halves (lane l and l^32 share p)
        if (b == 0) sel20 = s2; else sel21 = s2;
    }

    float lst0[16], lst1[16];
#pragma unroll
    for (int j = 0; j < 16; ++j) { lst0[j] = FMAXV; lst1[j] = FMAXV; }
    float cm0 = FMAXV, cm1 = FMAXV;

    for (int t = 0; t < TPW; ++t) {
        long n0 = (long)(gw * TPW + t) * NTILE;

        // A-fragment loads: row n = n0 + l31, k = 16*ks + 8*lh + j (coalesced)
        float av[4][8];
#pragma unroll
        for (int ks = 0; ks < 4; ++ks)
#pragma unroll
            for (int j = 0; j < 8; ++j)
                av[ks][j] = f2[(long)(16 * ks + 8 * lh + j) * HWD + n0 + l31];

        float fs = 0.f;
#pragma unroll
        for (int ks = 0; ks < 4; ++ks)
#pragma unroll
            for (int j = 0; j < 8; ++j)
                fs += av[ks][j] * av[ks][j];
        fs += __shfl_xor(fs, 32);  // lane l and l^32 hold same n, complementary k

        bf16x8 af[4];
#pragma unroll
        for (int ks = 0; ks < 4; ++ks)
#pragma unroll
            for (int j = 0; j < 8; ++j)
                af[ks][j] = f2bf(av[ks][j]);

        f32x16 acc0, acc1;
#pragma unroll
        for (int i = 0; i < 16; ++i) { acc0[i] = 0.f; acc1[i] = 0.f; }
#pragma unroll
        for (int ks = 0; ks < 4; ++ks) {
            acc0 = __builtin_amdgcn_mfma_f32_32x32x16_bf16(af[ks], selfrag[0][ks], acc0, 0, 0, 0);
            acc1 = __builtin_amdgcn_mfma_f32_32x32x16_bf16(af[ks], selfrag[1][ks], acc1, 0, 0, 0);
        }

        // f2sq for my 16 C-rows: row r = (i&3) + 8*(i>>2) + 4*lh, value lives in lane r
        float fsr[16];
#pragma unroll
        for (int i = 0; i < 16; ++i) {
            int r = (i & 3) + 8 * (i >> 2) + 4 * lh;
            fsr[i] = __shfl(fs, r);
        }

#pragma unroll
        for (int i = 0; i < 16; ++i) {
            float d0 = fmaxf(sel20 + fsr[i] - 2.f * acc0[i], 0.f);
            SCREEN(d0, lst0, cm0);
            float d1 = fmaxf(sel21 + fsr[i] - 2.f * acc1[i], 0.f);
            SCREEN(d1, lst1, cm1);
        }
    }

    // candidate layout: [p][wave][pair=lh][16]
    {
        long base0 = (((long)l31 * K1_WAVES + gw) * 2 + lh) * 16;
#pragma unroll
        for (int q = 0; q < 4; ++q)
            ((float4*)(cand + base0))[q] =
                make_float4(lst0[4*q], lst0[4*q+1], lst0[4*q+2], lst0[4*q+3]);
        long base1 = (((long)(l31 + 32) * K1_WAVES + gw) * 2 + lh) * 16;
#pragma unroll
        for (int q = 0; q < 4; ++q)
            ((float4*)(cand + base1))[q] =
                make_float4(lst1[4*q], lst1[4*q+1], lst1[4*q+2], lst1[4*q+3]);
    }
}

// K2: one block per p. Merge 65536 candidates -> exact 16 smallest -> sum.
__global__ __launch_bounds__(256) void k2_select(
    const float* __restrict__ cand, float* __restrict__ partial)
{
    const int p = blockIdx.x;
    const int tid = threadIdx.x;
    const int lane = tid & 63, wid = tid >> 6;
    const float4* base = (const float4*)(cand + (long)p * K1_WAVES * 32);

    float lst[16];
#pragma unroll
    for (int j = 0; j < 16; ++j) lst[j] = FMAXV;
    float cm = FMAXV;

    for (int it = 0; it < 64; ++it) {           // 64*256 float4 = 65536 floats
        float4 v = base[it * 256 + tid];
        float a0 = v.x, a1 = v.y, a2 = v.z, a3 = v.w;
        SCREEN(a0, lst, cm);
        SCREEN(a1, lst, cm);
        SCREEN(a2, lst, cm);
        SCREEN(a3, lst, cm);
    }

    __shared__ unsigned long long wmin[4];
    float sum = 0.f;
    for (int r = 0; r < 16; ++r) {
        // local argmin (static indexing)
        float m = lst[0]; int a = 0;
#pragma unroll
        for (int j = 1; j < 16; ++j)
            if (lst[j] < m) { m = lst[j]; a = j; }
        // non-negative floats: bit pattern order == value order; tie-break by slot
        unsigned long long key =
            ((unsigned long long)__float_as_uint(m) << 32) | (unsigned)(tid * 16 + a);
#pragma unroll
        for (int off = 32; off; off >>= 1) {
            unsigned long long o = __shfl_xor(key, off);
            if (o < key) key = o;
        }
        if (lane == 0) wmin[wid] = key;
        __syncthreads();
        unsigned long long gk = wmin[0];
#pragma unroll
        for (int w = 1; w < 4; ++w)
            if (wmin[w] < gk) gk = wmin[w];
        sum += __uint_as_float((unsigned)(gk >> 32));
        int slot = (int)(gk & 0xFFFFFFFFu);
        if ((slot >> 4) == tid) {
#pragma unroll
            for (int j = 0; j < 16; ++j)
                if (j == (slot & 15)) lst[j] = FMAXV;   // static index
        }
        __syncthreads();
    }
    if (tid == 0) partial[p] = sum;
}

__global__ void k3_final(const float* __restrict__ partial, float* __restrict__ out)
{
    float v = partial[threadIdx.x];   // 64 threads
#pragma unroll
    for (int off = 32; off; off >>= 1) v += __shfl_xor(v, off);
    if (threadIdx.x == 0) out[0] = -v / 1024.0f;   // mean over 64 rows x 16
}

extern "C" void kernel_launch(void* const* d_in, const int* in_sizes, int n_in,
                              void* d_out, int out_size, void* d_ws, size_t ws_size,
                              hipStream_t stream)
{
    const float* f1   = (const float*)d_in[0];
    const float* f2   = (const float*)d_in[1];
    const int*   nidx = (const int*)d_in[3];     // negative_indices (d_in[2] unused)
    float* out  = (float*)d_out;
    float* cand = (float*)d_ws;                          // 64*2048*32 floats = 16 MB
    float* partial = cand + (long)CD * K1_WAVES * 32;    // +64 floats

    k1_disttop<<<K1_BLOCKS, 256, 0, stream>>>(f1, f2, nidx, cand);
    k2_select<<<CD, 256, 0, stream>>>(cand, partial);
    k3_final<<<1, 64, 0, stream>>>(partial, out);
}